// Round 5
// baseline (4776.446 us; speedup 1.0000x reference)
//
#include <hip/hip_runtime.h>
#include <hip/hip_fp16.h>

#define BB 128
#define TT 500
#define HH 512
#define TWOH 1024
#define KB 16  // k-tiles of 32

typedef _Float16 f16x8 __attribute__((ext_vector_type(8)));
typedef float f32x4 __attribute__((ext_vector_type(4)));

// ws: u16 1MiB | hd fp16 [8 g][2 par][16 m][512 k] (512KiB) | flags i32 [8][2][32]
#define WS_U16_HALVES (TWOH * HH)
#define HD_HALVES (8 * 2 * 16 * HH)
#define NFLAGS (8 * 2 * 32)

__global__ void prep_kernel(const float* __restrict__ u,
                            const float* __restrict__ ht,
                            __half* __restrict__ u16, __half* __restrict__ hd,
                            int* __restrict__ flags) {
  int i = blockIdx.x * blockDim.x + threadIdx.x;
  if (i < WS_U16_HALVES) u16[i] = __float2half(u[i]);
  if (i < BB * HH) {  // parity-0 data <- h_0
    int R = i >> 9, k = i & 511;
    int g = R >> 4, m = R & 15;
    hd[((size_t)(g * 2 + 0) * 16 + m) * HH + k] = __float2half(ht[i]);
  }
  // flags[g][par][s]: par0 = 0 (h_0 present), par1 = INT_MIN (invalid).
  if (i < NFLAGS) flags[i] = ((i >> 5) & 1) ? (int)0x80000000 : 0;
}

#define LOADQ(K, OFFSTR)                                               \
  asm volatile("global_load_dwordx4 %0, %1, off offset:" OFFSTR        \
               " sc0 sc1"                                              \
               : "=v"(av[K])                                           \
               : "v"(pbase)                                            \
               : "memory");

// 256 blocks x 64 threads (1 wave, no LDS, no barriers). Block = one chain:
// group g=b>>5 (16 batch rows), col-slice s=b&31 (16 hidden cols, both gates).
// Lane: l15 = col offset AND A-frag row m; q = k-chunk / output row group.
__global__ __launch_bounds__(64, 1) void ligru_mfma(
    const float* __restrict__ wx, const __half* __restrict__ u16,
    const float* __restrict__ ht, const float* __restrict__ mask,
    float* __restrict__ out, __half* __restrict__ hd, int* __restrict__ flags) {
  const int lane = threadIdx.x;
  const int l15 = lane & 15;
  const int q = lane >> 4;
  const int b = blockIdx.x;
  const int g = b >> 5;
  const int s = b & 31;
  const int row0 = g * 16;
  const int j = s * 16 + l15;

  // B-frags (u), persistent: 128 VGPR. nt0: gate row j (at); nt1: row 512+j.
  f16x8 bf[KB][2];
#pragma unroll
  for (int kb = 0; kb < KB; ++kb) {
    bf[kb][0] = *(const f16x8*)(u16 + (size_t)j * HH + kb * 32 + q * 8);
    bf[kb][1] = *(const f16x8*)(u16 + (size_t)(HH + j) * HH + kb * 32 + q * 8);
  }

  // per-lane persistent state: rows m=4q+r, col j; fp32 master h
  float hreg[4], mreg[4];
#pragma unroll
  for (int r = 0; r < 4; ++r) {
    size_t off = (size_t)(row0 + 4 * q + r) * HH + j;
    mreg[r] = mask[off];
    hreg[r] = ht[off];
  }

  const size_t BTH = (size_t)BB * TT * HH;
  float* out_h = out;
  float* out_z = out + BTH;
  float* out_a = out + 2 * BTH;
  float* out_hc = out + 3 * BTH;

  for (int t = 0; t < TT; ++t) {
    // wx prefetch (h-independent; in flight across the poll)
    float wxa[4], wxz[4];
#pragma unroll
    for (int r = 0; r < 4; ++r) {
      size_t base = ((size_t)(row0 + 4 * q + r) * TT + t) * TWOH + j;
      wxa[r] = wx[base];
      wxz[r] = wx[base + HH];
    }

    // ---- poll 32 producer flags (128 B; acquire on the winning round)
    int* fl = flags + (g * 2 + (t & 1)) * 32;
    {
      int bail = 0;
      for (;;) {
        int f = __hip_atomic_load(fl + (lane & 31), __ATOMIC_ACQUIRE,
                                  __HIP_MEMORY_SCOPE_AGENT);
        if (__all(f == t)) break;
        if (++bail > (1 << 16)) break;
        __builtin_amdgcn_s_sleep(1);
      }
    }

    // ---- stream h_t (16 KB/wave): lane reads row m=l15, 16B per k-tile
    const uint4* pbase =
        (const uint4*)(hd + ((size_t)(g * 2 + (t & 1)) * 16 + l15) * HH) + q;
    uint4 av[KB];
    LOADQ(0, "0") LOADQ(1, "64") LOADQ(2, "128") LOADQ(3, "192")
    LOADQ(4, "256") LOADQ(5, "320") LOADQ(6, "384") LOADQ(7, "448")
    LOADQ(8, "512") LOADQ(9, "576") LOADQ(10, "640") LOADQ(11, "704")
    LOADQ(12, "768") LOADQ(13, "832") LOADQ(14, "896") LOADQ(15, "960")

    f32x4 acc0 = {0.f, 0.f, 0.f, 0.f}, acc1 = {0.f, 0.f, 0.f, 0.f};
    asm volatile("s_waitcnt vmcnt(8)" ::: "memory");
    __builtin_amdgcn_sched_barrier(0);
#pragma unroll
    for (int kb = 0; kb < 8; ++kb) {
      f16x8 af = __builtin_bit_cast(f16x8, av[kb]);
      acc0 = __builtin_amdgcn_mfma_f32_16x16x32_f16(af, bf[kb][0], acc0, 0, 0, 0);
      acc1 = __builtin_amdgcn_mfma_f32_16x16x32_f16(af, bf[kb][1], acc1, 0, 0, 0);
    }
    asm volatile("s_waitcnt vmcnt(0)" ::: "memory");
    __builtin_amdgcn_sched_barrier(0);
#pragma unroll
    for (int kb = 8; kb < KB; ++kb) {
      f16x8 af = __builtin_bit_cast(f16x8, av[kb]);
      acc0 = __builtin_amdgcn_mfma_f32_16x16x32_f16(af, bf[kb][0], acc0, 0, 0, 0);
      acc1 = __builtin_amdgcn_mfma_f32_16x16x32_f16(af, bf[kb][1], acc1, 0, 0, 0);
    }

    // ---- epilogue: h data stores, release flag, then bulk outputs
    unsigned* hdst32 =
        (unsigned*)(hd + (size_t)(g * 2 + ((t + 1) & 1)) * 16 * HH);
    float atv[4], ztv[4], hcv[4];
#pragma unroll
    for (int r = 0; r < 4; ++r) {
      float at = acc0[r] + wxa[r];
      float ztp = acc1[r] + wxz[r];
      float zt = 1.f / (1.f + __expf(-ztp));
      float hc = fmaxf(at, 0.f) * mreg[r];
      float hn = hreg[r] * zt + (1.f - zt) * hc;
      hreg[r] = hn;
      float hn_nbr = __shfl_xor(hn, 1);  // col pair (j even | j odd)
      if ((l15 & 1) == 0) {
        unsigned pk = (unsigned)__half_as_ushort(__float2half(hn)) |
                      ((unsigned)__half_as_ushort(__float2half(hn_nbr)) << 16);
        __hip_atomic_store(hdst32 + (((4 * q + r) * HH + j) >> 1), pk,
                           __ATOMIC_RELAXED, __HIP_MEMORY_SCOPE_AGENT);
      }
      atv[r] = at;
      ztv[r] = zt;
      hcv[r] = hc;
    }
    if (lane == 0) {
      int* fl2 = flags + (g * 2 + ((t + 1) & 1)) * 32;
      __hip_atomic_store(fl2 + s, t + 1, __ATOMIC_RELEASE,
                         __HIP_MEMORY_SCOPE_AGENT);
    }
    // outputs after the flag: off the recurrence critical path
#pragma unroll
    for (int r = 0; r < 4; ++r) {
      size_t oidx = ((size_t)(row0 + 4 * q + r) * TT + t) * HH + j;
      __builtin_nontemporal_store(hreg[r], &out_h[oidx]);
      __builtin_nontemporal_store(ztv[r], &out_z[oidx]);
      __builtin_nontemporal_store(atv[r], &out_a[oidx]);
      __builtin_nontemporal_store(hcv[r], &out_hc[oidx]);
    }
  }
}

extern "C" void kernel_launch(void* const* d_in, const int* in_sizes, int n_in,
                              void* d_out, int out_size, void* d_ws,
                              size_t ws_size, hipStream_t stream) {
  const float* wx = (const float*)d_in[0];
  const float* u = (const float*)d_in[1];
  const float* ht = (const float*)d_in[2];
  const float* mask = (const float*)d_in[3];
  float* out = (float*)d_out;

  __half* u16 = (__half*)d_ws;
  __half* hd = u16 + WS_U16_HALVES;
  int* flags = (int*)(hd + HD_HALVES);

  hipLaunchKernelGGL(prep_kernel, dim3(2048), dim3(256), 0, stream, u, ht, u16,
                     hd, flags);
  hipLaunchKernelGGL(ligru_mfma, dim3(256), dim3(64), 0, stream, wx, u16, ht,
                     mask, out, hd, flags);
}

// Round 6
// 2465.222 us; speedup vs baseline: 1.9375x; 1.9375x over previous
//
#include <hip/hip_runtime.h>
#include <hip/hip_fp16.h>

#define BB 128
#define TT 500
#define HH 512
#define TWOH 1024
#define KB 16  // k-tiles of 32

typedef _Float16 f16x8 __attribute__((ext_vector_type(8)));
typedef float f32x4 __attribute__((ext_vector_type(4)));
typedef unsigned long long u64;

// ws: u16 1 MiB | hx u64 [8 g][2 par][16 m][256 k2] (512 KiB)
// hx qword = (tag<<32) | (fp16 h[m][2k2+1] << 16) | fp16 h[m][2k2]
#define WS_U16_HALVES (TWOH * HH)
#define HX_QWORDS (8 * 2 * 16 * 256)

__global__ void prep_kernel(const float* __restrict__ u,
                            const float* __restrict__ ht,
                            __half* __restrict__ u16, u64* __restrict__ hx) {
  int i = blockIdx.x * blockDim.x + threadIdx.x;
  if (i < WS_U16_HALVES) u16[i] = __float2half(u[i]);
  if (i < HX_QWORDS) {
    int g = i >> 13, rem = i & 8191;
    int par = rem >> 12, m = (rem >> 8) & 15, k2 = rem & 255;
    u64 val;
    if (par == 0) {  // h_0, tag 0
      int R = g * 16 + m;
      unsigned lo =
          (unsigned)__half_as_ushort(__float2half(ht[(size_t)R * HH + 2 * k2])) |
          ((unsigned)__half_as_ushort(
               __float2half(ht[(size_t)R * HH + 2 * k2 + 1]))
           << 16);
      val = (u64)lo;
    } else {
      val = 0xFFFFFFFF00000000ull;  // sentinel (replay-stale safe)
    }
    hx[i] = val;
  }
}

// 32 blocks x 256 threads (4 waves). Block b: col-slice s=b>>2 (64 cols, both
// gates), groups gA=2*(b&3), gB=gA+1 interleaved (propagation of one chain
// hides under the other's compute). The block cooperatively polls the group's
// tagged h (fused flag+data, relaxed agent atomics, no fences), stages the
// payload into XOR-swizzled LDS once, and all 4 waves read A-frags from LDS:
// MALL broadcast fan-out per group drops 32 -> 8 consumers.
__global__ __launch_bounds__(256, 1) void ligru_mfma(
    const float* __restrict__ wx, const __half* __restrict__ u16,
    const float* __restrict__ ht, const float* __restrict__ mask,
    float* __restrict__ out, u64* __restrict__ hx) {
  const int tid = threadIdx.x;
  const int lane = tid & 63;
  const int w = tid >> 6;
  const int l15 = lane & 15;
  const int q = lane >> 4;
  const int b = blockIdx.x;
  const int p = b & 3;
  const int s = b >> 2;
  const int gI[2] = {2 * p, 2 * p + 1};
  const int row0[2] = {gI[0] * 16, gI[1] * 16};
  const int j = s * 64 + w * 16 + l15;  // this lane's hidden col

  __shared__ alignas(16) char hsm[2][16 * 1024];  // [G][m][k] fp16, XOR-swz

  // B-frags (u), persistent (128 VGPR), shared by both chains.
  f16x8 bf[KB][2];
#pragma unroll
  for (int kb = 0; kb < KB; ++kb) {
    bf[kb][0] = *(const f16x8*)(u16 + (size_t)j * HH + kb * 32 + q * 8);
    bf[kb][1] = *(const f16x8*)(u16 + (size_t)(HH + j) * HH + kb * 32 + q * 8);
  }

  // per-lane persistent state: rows m=4q+r, col j; fp32 master h
  float hreg[2][4], mreg[2][4];
#pragma unroll
  for (int G = 0; G < 2; ++G)
#pragma unroll
    for (int r = 0; r < 4; ++r) {
      size_t off = (size_t)(row0[G] + 4 * q + r) * HH + j;
      mreg[G][r] = mask[off];
      hreg[G][r] = ht[off];
    }

  const size_t BTH = (size_t)BB * TT * HH;
  float* out_h = out;
  float* out_z = out + BTH;
  float* out_a = out + 2 * BTH;
  float* out_hc = out + 3 * BTH;

  for (int t = 0; t < TT; ++t) {
    // wx prefetch for both chains (h-independent)
    float wxa[2][4], wxz[2][4];
#pragma unroll
    for (int G = 0; G < 2; ++G)
#pragma unroll
      for (int r = 0; r < 4; ++r) {
        size_t base = ((size_t)(row0[G] + 4 * q + r) * TT + t) * TWOH + j;
        wxa[G][r] = wx[base];
        wxz[G][r] = wx[base + HH];
      }

#pragma unroll
    for (int G = 0; G < 2; ++G) {
      // ---- cooperative tagged poll: thread tid owns (m=pp, k2=tid) qwords
      const u64* src = hx + (size_t)(gI[G] * 2 + (t & 1)) * 4096 + tid;
      u64 qw[16];
      {
        int bail = 0;
        // cheap readiness wait: 1 qword/thread (row 15 = late producer store)
        for (;;) {
          u64 x = __hip_atomic_load(src + 15 * 256, __ATOMIC_RELAXED,
                                    __HIP_MEMORY_SCOPE_AGENT);
          if (__all((unsigned)(x >> 32) == (unsigned)t) || ++bail > (1 << 16))
            break;
          __builtin_amdgcn_s_sleep(2);
        }
        // authoritative full read + per-word tag check (retry if torn)
        bail = 0;
        for (;;) {
          bool ok = true;
#pragma unroll
          for (int pp = 0; pp < 16; ++pp)
            qw[pp] = __hip_atomic_load(src + pp * 256, __ATOMIC_RELAXED,
                                       __HIP_MEMORY_SCOPE_AGENT);
#pragma unroll
          for (int pp = 0; pp < 16; ++pp)
            ok &= ((unsigned)(qw[pp] >> 32) == (unsigned)t);
          if (__all(ok) || ++bail > (1 << 14)) break;
          __builtin_amdgcn_s_sleep(1);
        }
      }

      // ---- stage payload into LDS (b32 each row, XOR swizzle; conflict-free)
      {
        char* dst = hsm[G];
#pragma unroll
        for (int pp = 0; pp < 16; ++pp) {
          unsigned lo = (unsigned)qw[pp];
          *(unsigned*)(dst + ((pp * 1024 + tid * 4) ^ ((pp & 7) << 4))) = lo;
        }
      }
      __syncthreads();

      // ---- MFMA: A row=l15, k-chunk q from LDS; both gate tiles
      f32x4 acc0 = {0.f, 0.f, 0.f, 0.f}, acc1 = {0.f, 0.f, 0.f, 0.f};
#pragma unroll
      for (int kb = 0; kb < KB; ++kb) {
        int off = (l15 * 1024 + kb * 64 + q * 16) ^ ((l15 & 7) << 4);
        f16x8 af = *(const f16x8*)(hsm[G] + off);
        acc0 = __builtin_amdgcn_mfma_f32_16x16x32_f16(af, bf[kb][0], acc0, 0, 0, 0);
        acc1 = __builtin_amdgcn_mfma_f32_16x16x32_f16(af, bf[kb][1], acc1, 0, 0, 0);
      }

      // ---- epilogue: tagged h stores first (critical path), outputs after
      u64* dstbase = hx + (size_t)(gI[G] * 2 + ((t + 1) & 1)) * 4096;
      const u64 tagn = (u64)(unsigned)(t + 1) << 32;
      float atv[4], ztv[4], hcv[4];
#pragma unroll
      for (int r = 0; r < 4; ++r) {
        float at = acc0[r] + wxa[G][r];
        float ztp = acc1[r] + wxz[G][r];
        float zt = 1.f / (1.f + __expf(-ztp));
        float hc = fmaxf(at, 0.f) * mreg[G][r];
        float hn = hreg[G][r] * zt + (1.f - zt) * hc;
        hreg[G][r] = hn;
        float hn_nbr = __shfl_xor(hn, 1);  // col pair (j even | j odd)
        if ((l15 & 1) == 0) {
          unsigned lo = (unsigned)__half_as_ushort(__float2half(hn)) |
                        ((unsigned)__half_as_ushort(__float2half(hn_nbr)) << 16);
          __hip_atomic_store(dstbase + (4 * q + r) * 256 + (j >> 1), tagn | lo,
                             __ATOMIC_RELAXED, __HIP_MEMORY_SCOPE_AGENT);
        }
        atv[r] = at;
        ztv[r] = zt;
        hcv[r] = hc;
      }
#pragma unroll
      for (int r = 0; r < 4; ++r) {
        size_t oidx = ((size_t)(row0[G] + 4 * q + r) * TT + t) * HH + j;
        __builtin_nontemporal_store(hreg[G][r], &out_h[oidx]);
        __builtin_nontemporal_store(ztv[r], &out_z[oidx]);
        __builtin_nontemporal_store(atv[r], &out_a[oidx]);
        __builtin_nontemporal_store(hcv[r], &out_hc[oidx]);
      }
      // hsm[G] is rewritten only after the OTHER phase's barrier -> no WAR.
    }
  }
}

extern "C" void kernel_launch(void* const* d_in, const int* in_sizes, int n_in,
                              void* d_out, int out_size, void* d_ws,
                              size_t ws_size, hipStream_t stream) {
  const float* wx = (const float*)d_in[0];
  const float* u = (const float*)d_in[1];
  const float* ht = (const float*)d_in[2];
  const float* mask = (const float*)d_in[3];
  float* out = (float*)d_out;

  __half* u16 = (__half*)d_ws;
  u64* hx = (u64*)(u16 + WS_U16_HALVES);

  hipLaunchKernelGGL(prep_kernel, dim3(2048), dim3(256), 0, stream, u, ht, u16,
                     hx);
  hipLaunchKernelGGL(ligru_mfma, dim3(32), dim3(256), 0, stream, wx, u16, ht,
                     mask, out, hx);
}

// Round 7
// 2013.011 us; speedup vs baseline: 2.3728x; 1.2246x over previous
//
#include <hip/hip_runtime.h>
#include <hip/hip_fp16.h>

#define BB 128
#define TT 500
#define HH 512
#define TWOH 1024
#define KB 16  // k-tiles of 32

typedef _Float16 f16x8 __attribute__((ext_vector_type(8)));
typedef float f32x4 __attribute__((ext_vector_type(4)));
typedef unsigned long long u64;

// ws: u16 1 MiB | hx u32 [8 g][2 par][16 m][512 k] (512 KiB)
// hx word = (tag16 << 16) | fp16 h[m][k]   (tag = step, 0..500; 0xFFFF = inv)
#define WS_U16_HALVES (TWOH * HH)
#define HX_WORDS (8 * 2 * 16 * HH)

__global__ void prep_kernel(const float* __restrict__ u,
                            const float* __restrict__ ht,
                            __half* __restrict__ u16,
                            unsigned* __restrict__ hx) {
  int i = blockIdx.x * blockDim.x + threadIdx.x;
  if (i < WS_U16_HALVES) u16[i] = __float2half(u[i]);
  if (i < HX_WORDS) {
    int g = i >> 14, rem = i & 16383;
    int par = rem >> 13, m = (rem >> 9) & 15, k = rem & 511;
    unsigned val;
    if (par == 0) {  // h_0, tag 0 in high halfword
      int R = g * 16 + m;
      val = (unsigned)__half_as_ushort(__float2half(ht[(size_t)R * HH + k]));
    } else {
      val = 0xFFFF0000u;  // sentinel (never matches; replay-stale safe)
    }
    hx[i] = val;
  }
}

#define TAGMASK 0xFFFF0000FFFF0000ull

// Tagged cooperative read: thread tid reads qword tid of each of 16 rows
// (row = 2 KB; per-instr 512 B dense per wave). Each dword self-validates.
#define CHECK_RETRY(QW, GIDX, PARC, TCUR)                                      \
  {                                                                            \
    const u64* _src = (const u64*)hx + ((size_t)((GIDX)*2 + (PARC)) << 12) + tid; \
    const u64 _tagp = ((u64)(unsigned)(TCUR) << 48) | ((u64)(unsigned)(TCUR) << 16); \
    bool _ok = true;                                                           \
    _Pragma("unroll") for (int pp = 0; pp < 16; ++pp)                          \
        _ok &= ((QW[pp] & TAGMASK) == _tagp);                                  \
    int _bail = 0;                                                             \
    while (!__all(_ok)) {                                                      \
      __builtin_amdgcn_s_sleep(1);                                             \
      _Pragma("unroll") for (int pp = 0; pp < 16; ++pp)                        \
          QW[pp] = __hip_atomic_load(_src + pp * 256, __ATOMIC_RELAXED,        \
                                     __HIP_MEMORY_SCOPE_AGENT);                \
      _ok = true;                                                              \
      _Pragma("unroll") for (int pp = 0; pp < 16; ++pp)                        \
          _ok &= ((QW[pp] & TAGMASK) == _tagp);                                \
      if (++_bail > (1 << 15)) break;                                          \
    }                                                                          \
  }

#define PREFETCH(QW, GIDX, PARN)                                               \
  {                                                                            \
    const u64* _srcn = (const u64*)hx + ((size_t)((GIDX)*2 + (PARN)) << 12) + tid; \
    _Pragma("unroll") for (int pp = 0; pp < 16; ++pp)                          \
        QW[pp] = __hip_atomic_load(_srcn + pp * 256, __ATOMIC_RELAXED,         \
                                   __HIP_MEMORY_SCOPE_AGENT);                  \
  }

// One phase of chain G at time TCUR. QWc holds (possibly) prefetched tagged
// data for (G, TCUR); QWn gets the prefetch for the NEXT phase (G^1, PARN).
#define PHASE(G, QWc, QWn, TCUR, PARN, TNEXT_UNUSED)                           \
  {                                                                            \
    CHECK_RETRY(QWc, gI[G], ((TCUR)&1), (TCUR))                                \
    { /* stage payload halves into XOR-swizzled LDS */                         \
      char* _dst = hsm[G];                                                     \
      _Pragma("unroll") for (int pp = 0; pp < 16; ++pp) {                      \
        unsigned _d0 = (unsigned)QWc[pp], _d1 = (unsigned)(QWc[pp] >> 32);     \
        unsigned _pk = (_d0 & 0xFFFFu) | (_d1 << 16);                          \
        *(unsigned*)(_dst + ((pp * 1024 + tid * 4) ^ ((pp & 7) << 4))) = _pk;  \
      }                                                                        \
    }                                                                          \
    __syncthreads();                                                           \
    PREFETCH(QWn, gI[(G) ^ 1], (PARN))                                         \
    f32x4 acc0 = {0.f, 0.f, 0.f, 0.f}, acc1 = {0.f, 0.f, 0.f, 0.f};           \
    _Pragma("unroll") for (int kb = 0; kb < KB; ++kb) {                        \
      int _off = (l15 * 1024 + kb * 64 + q * 16) ^ ((l15 & 7) << 4);           \
      f16x8 _af = *(const f16x8*)(hsm[G] + _off);                              \
      acc0 = __builtin_amdgcn_mfma_f32_16x16x32_f16(_af, bf[kb][0], acc0, 0, 0, 0); \
      acc1 = __builtin_amdgcn_mfma_f32_16x16x32_f16(_af, bf[kb][1], acc1, 0, 0, 0); \
    }                                                                          \
    /* epilogue: tagged per-dword h stores first, outputs after */             \
    unsigned* _hd = hx + ((size_t)(gI[G] * 2 + (((TCUR) + 1) & 1)) << 13);     \
    const unsigned _tg = (unsigned)((TCUR) + 1) << 16;                         \
    float _atv[4], _ztv[4], _hcv[4];                                           \
    _Pragma("unroll") for (int r = 0; r < 4; ++r) {                            \
      float _at = acc0[r] + wxa[G][r];                                         \
      float _zp = acc1[r] + wxz[G][r];                                         \
      float _zt = 1.f / (1.f + __expf(-_zp));                                  \
      float _hc = fmaxf(_at, 0.f) * mreg[G][r];                                \
      float _hn = hreg[G][r] * _zt + (1.f - _zt) * _hc;                        \
      hreg[G][r] = _hn;                                                        \
      __hip_atomic_store(_hd + (4 * q + r) * HH + j,                           \
                         _tg | (unsigned)__half_as_ushort(__float2half(_hn)),  \
                         __ATOMIC_RELAXED, __HIP_MEMORY_SCOPE_AGENT);          \
      _atv[r] = _at; _ztv[r] = _zt; _hcv[r] = _hc;                             \
    }                                                                          \
    _Pragma("unroll") for (int r = 0; r < 4; ++r) {                            \
      size_t _oi = ((size_t)(row0[G] + 4 * q + r) * TT + (TCUR)) * HH + j;     \
      __builtin_nontemporal_store(hreg[G][r], &out_h[_oi]);                    \
      __builtin_nontemporal_store(_ztv[r], &out_z[_oi]);                       \
      __builtin_nontemporal_store(_atv[r], &out_a[_oi]);                       \
      __builtin_nontemporal_store(_hcv[r], &out_hc[_oi]);                      \
    }                                                                          \
  }

// 32 blocks x 256 threads (4 waves). Block b: col-slice s=b>>2 (64 cols, both
// gates), chains gA=2*(b&3), gB=gA+1 interleaved. Single-pass tagged poll
// (data == flag), one-phase-lookahead register prefetch hides the MALL RT.
__global__ __launch_bounds__(256, 1) void ligru_mfma(
    const float* __restrict__ wx, const __half* __restrict__ u16,
    const float* __restrict__ ht, const float* __restrict__ mask,
    float* __restrict__ out, unsigned* __restrict__ hx) {
  const int tid = threadIdx.x;
  const int lane = tid & 63;
  const int w = tid >> 6;
  const int l15 = lane & 15;
  const int q = lane >> 4;
  const int b = blockIdx.x;
  const int p = b & 3;
  const int s = b >> 2;
  const int gI[2] = {2 * p, 2 * p + 1};
  const int row0[2] = {gI[0] * 16, gI[1] * 16};
  const int j = s * 64 + w * 16 + l15;  // this lane's hidden col

  __shared__ alignas(16) char hsm[2][16 * 1024];  // [G][m][k] fp16, XOR-swz

  // B-frags (u), persistent (128 VGPR), shared by both chains.
  f16x8 bf[KB][2];
#pragma unroll
  for (int kb = 0; kb < KB; ++kb) {
    bf[kb][0] = *(const f16x8*)(u16 + (size_t)j * HH + kb * 32 + q * 8);
    bf[kb][1] = *(const f16x8*)(u16 + (size_t)(HH + j) * HH + kb * 32 + q * 8);
  }

  // per-lane persistent state: rows m=4q+r, col j; fp32 master h
  float hreg[2][4], mreg[2][4];
#pragma unroll
  for (int G = 0; G < 2; ++G)
#pragma unroll
    for (int r = 0; r < 4; ++r) {
      size_t off = (size_t)(row0[G] + 4 * q + r) * HH + j;
      mreg[G][r] = mask[off];
      hreg[G][r] = ht[off];
    }

  const size_t BTH = (size_t)BB * TT * HH;
  float* out_h = out;
  float* out_z = out + BTH;
  float* out_a = out + 2 * BTH;
  float* out_hc = out + 3 * BTH;

  u64 qwA[16], qwB[16];
  PREFETCH(qwA, gI[0], 0)  // h_A(0): written by prep, tag 0

  for (int t = 0; t < TT; ++t) {
    // wx prefetch for both chains (h-independent; in flight across checks)
    float wxa[2][4], wxz[2][4];
#pragma unroll
    for (int G = 0; G < 2; ++G)
#pragma unroll
      for (int r = 0; r < 4; ++r) {
        size_t base = ((size_t)(row0[G] + 4 * q + r) * TT + t) * TWOH + j;
        wxa[G][r] = wx[base];
        wxz[G][r] = wx[base + HH];
      }

    PHASE(0, qwA, qwB, t, (t & 1), 0)        // consumes A(t); prefetch B(t)
    PHASE(1, qwB, qwA, t, ((t + 1) & 1), 0)  // consumes B(t); prefetch A(t+1)
  }
}

extern "C" void kernel_launch(void* const* d_in, const int* in_sizes, int n_in,
                              void* d_out, int out_size, void* d_ws,
                              size_t ws_size, hipStream_t stream) {
  const float* wx = (const float*)d_in[0];
  const float* u = (const float*)d_in[1];
  const float* ht = (const float*)d_in[2];
  const float* mask = (const float*)d_in[3];
  float* out = (float*)d_out;

  __half* u16 = (__half*)d_ws;
  unsigned* hx = (unsigned*)(u16 + WS_U16_HALVES);

  hipLaunchKernelGGL(prep_kernel, dim3(2048), dim3(256), 0, stream, u, ht, u16,
                     hx);
  hipLaunchKernelGGL(ligru_mfma, dim3(32), dim3(256), 0, stream, wx, u16, ht,
                     mask, out, hx);
}